// Round 8
// baseline (674.273 us; speedup 1.0000x reference)
//
#include <hip/hip_runtime.h>
#include <math.h>

typedef _Float16 h8 __attribute__((ext_vector_type(8)));
typedef float f4 __attribute__((ext_vector_type(4)));

#define BATCH 8192

// Swizzle on amp index (float2 units): XOR bits 3:1 with hash of upper bits.
// (validated r4/r6)
#define SWZA(i) ((i) ^ (((((i) >> 4) ^ ((i) >> 7) ^ ((i) >> 10)) & 7) << 1))

// ---------------------------------------------------------------------------
// Stage matrices as MFMA B-operands, split precision (hi + lo*2^11 f16).
// Bit-identical doubles to r6 (validated), but the 24 redundant double-trig
// calls per thread are computed once per block by 12 threads via LDS.
// ---------------------------------------------------------------------------
__global__ void build_mats(const float* __restrict__ params, _Float16* __restrict__ ws) {
  __shared__ double tg[4][6];  // per gate j: c, sn, ca, sa, cb, sb
  int s = blockIdx.x, layer = s / 3, axis = s % 3;
  int t = threadIdx.x, n = t >> 4, col = t & 15;

  if (t < 12) {
    int j = t / 3, which = t % 3;
    int q = (axis == 0) ? (11 - j) : (axis == 1) ? (7 - j) : (3 - j);
    const float* pp = params + (layer * 12 + q) * 3;
    double phi = pp[0], th = pp[1], om = pp[2];
    if (which == 0) { tg[j][0] = cos(0.5 * th);         tg[j][1] = sin(0.5 * th); }
    if (which == 1) { tg[j][2] = cos(0.5 * (phi + om)); tg[j][3] = sin(0.5 * (phi + om)); }
    if (which == 2) { tg[j][4] = cos(0.5 * (phi - om)); tg[j][5] = sin(0.5 * (phi - om)); }
  }
  __syncthreads();

  double Er = 1.0, Ei = 0.0;
  #pragma unroll
  for (int j = 0; j < 4; ++j) {
    double c = tg[j][0], sn = tg[j][1];
    double ca = tg[j][2], sa = tg[j][3], cb = tg[j][4], sb = tg[j][5];
    int nb = (n >> j) & 1, cbit = (col >> j) & 1;
    double mr, mi;
    if (!nb) {
      if (!cbit) { mr =  ca * c;  mi = -sa * c; }
      else       { mr = -cb * sn; mi = -sb * sn; }
    } else {
      if (!cbit) { mr =  cb * sn; mi = -sb * sn; }
      else       { mr =  ca * c;  mi =  sa * c; }
    }
    double nr = Er * mr - Ei * mi, ni = Er * mi + Ei * mr;
    Er = nr; Ei = ni;
  }
  int a_;
  if (axis == 0 && layer > 0) {           // CNOT fold: Gray slot order
    int kb = col >> 2, ll = col & 3;
    a_ = kb * 4 + ((ll ^ (ll >> 1)) ^ ((kb & 1) << 1));
  } else a_ = col;
  _Float16* reh = ws + s * 2048;
  _Float16* rel = reh + 512;
  _Float16* imh = reh + 1024;
  _Float16* iml = reh + 1536;
  int o0 = n * 32 + 2 * a_, o1 = o0 + 1;
  float v; _Float16 h;
  v = (float)Er;  h = (_Float16)v; reh[o0] = h; rel[o0] = (_Float16)((v - (float)h) * 2048.f);
  v = (float)-Ei; h = (_Float16)v; reh[o1] = h; rel[o1] = (_Float16)((v - (float)h) * 2048.f);
  v = (float)Ei;  h = (_Float16)v; imh[o0] = h; iml[o0] = (_Float16)((v - (float)h) * 2048.f);
  v = (float)Er;  h = (_Float16)v; imh[o1] = h; iml[o1] = (_Float16)((v - (float)h) * 2048.f);
}

// ---- 3-way split: v = h0 + h1*2^-11 + h2*2^-22 (parts f16, lo pre-scaled) ----
__device__ __forceinline__ void split3(float v, _Float16& h0, _Float16& h1, _Float16& h2) {
  h0 = (_Float16)v;
  float r0 = v - (float)h0;
  h1 = (_Float16)(r0 * 2048.f);
  float r1 = r0 - (float)h1 * (1.f / 2048.f);
  h2 = (_Float16)(r1 * 4194304.f);
}

// 10-MFMA complex matvec: A 3-split x B 2-split, dropped terms <= 2^-33.
__device__ __forceinline__ void cmatvec(const h8& a0, const h8& a1, const h8& a2,
    const h8& bRh, const h8& bRl, const h8& bIh, const h8& bIl,
    f4& outr, f4& outi) {
  f4 z = {0.f, 0.f, 0.f, 0.f};
  f4 mr  = __builtin_amdgcn_mfma_f32_16x16x32_f16(a0, bRh, z, 0, 0, 0);
  f4 cr  = __builtin_amdgcn_mfma_f32_16x16x32_f16(a1, bRh, z, 0, 0, 0);
  cr     = __builtin_amdgcn_mfma_f32_16x16x32_f16(a0, bRl, cr, 0, 0, 0);
  f4 c2r = __builtin_amdgcn_mfma_f32_16x16x32_f16(a2, bRh, z, 0, 0, 0);
  c2r    = __builtin_amdgcn_mfma_f32_16x16x32_f16(a1, bRl, c2r, 0, 0, 0);
  f4 mi  = __builtin_amdgcn_mfma_f32_16x16x32_f16(a0, bIh, z, 0, 0, 0);
  f4 ci  = __builtin_amdgcn_mfma_f32_16x16x32_f16(a1, bIh, z, 0, 0, 0);
  ci     = __builtin_amdgcn_mfma_f32_16x16x32_f16(a0, bIl, ci, 0, 0, 0);
  f4 c2i = __builtin_amdgcn_mfma_f32_16x16x32_f16(a2, bIh, z, 0, 0, 0);
  c2i    = __builtin_amdgcn_mfma_f32_16x16x32_f16(a1, bIl, c2i, 0, 0, 0);
  const float sc = 1.f / 2048.f, sc2 = 1.f / 4194304.f;
  #pragma unroll
  for (int j = 0; j < 4; ++j) {
    outr[j] = fmaf(c2r[j], sc2, fmaf(cr[j], sc, mr[j]));
    outi[j] = fmaf(c2i[j], sc2, fmaf(ci[j], sc, mi[j]));
  }
}

// ---------------------------------------------------------------------------
// r6 structure verbatim (fused L->M + H per layer, 2 LDS round trips,
// 4 barriers, CNOT folds), with 3-split A operands everywhere.
// ---------------------------------------------------------------------------
__global__ __launch_bounds__(256, 4) void circuit_kernel(
    const float* __restrict__ x, const _Float16* __restrict__ mats,
    const float* __restrict__ W, const float* __restrict__ bias,
    float* __restrict__ out) {
  __shared__ __align__(16) float2 st[4096];
  __shared__ float red[64];

  const int b = blockIdx.x;
  const int tid = threadIdx.x;
  const int lane = tid & 63, w = tid >> 6;
  const int r = lane & 15, kb = lane >> 4;

  // ---- init: product state of the data-encoding RY layer (r6 verbatim) ----
  float cs[12], sn_[12];
  #pragma unroll
  for (int q = 0; q < 12; ++q) {
    float sv, cv;
    sincosf(0.5f * x[b * 12 + q], &sv, &cv);
    cs[11 - q] = cv; sn_[11 - q] = sv;
  }
  {
    int hb = (w << 6) | lane;
    float basep = 1.f;
    #pragma unroll
    for (int i = 0; i < 8; ++i) basep *= ((hb >> i) & 1) ? sn_[4 + i] : cs[4 + i];
    float p2[4], q2[4];
    #pragma unroll
    for (int v = 0; v < 4; ++v) {
      p2[v] = ((v & 1) ? sn_[0] : cs[0]) * ((v & 2) ? sn_[1] : cs[1]);
      q2[v] = ((v & 1) ? sn_[2] : cs[2]) * ((v & 2) ? sn_[3] : cs[3]) * basep;
    }
    #pragma unroll
    for (int g = 0; g < 4; ++g) {
      int idx = w * 1024 + lane * 16 + g * 4;
      float a0 = q2[g] * p2[0], a1 = q2[g] * p2[1];
      float a2 = q2[g] * p2[2], a3 = q2[g] * p2[3];
      *(float4*)&st[SWZA(idx)]     = make_float4(a0, 0.f, a1, 0.f);
      *(float4*)&st[SWZA(idx + 2)] = make_float4(a2, 0.f, a3, 0.f);
    }
  }
  __syncthreads();

  // fold-read constants (r6 verbatim)
  const int g4r = r ^ (r >> 1);
  const int kb0 = kb & 1, kb1 = kb >> 1, m0 = r & 1;
  const int ob = ((kb1 ^ m0) << 1) | (kb0 ^ kb1);
  const int bo = r * 32 + kb * 8;

  for (int layer = 0; layer < 6; ++layer) {
    // ======== phase 1: L-stage (fold read) fused with M-stage ========
    const _Float16* mbL = mats + (layer * 3 + 0) * 2048;
    const _Float16* mbM = mats + (layer * 3 + 1) * 2048;
    h8 LbRh = *(const h8*)(mbL + bo),        LbRl = *(const h8*)(mbL + 512 + bo);
    h8 LbIh = *(const h8*)(mbL + 1024 + bo), LbIl = *(const h8*)(mbL + 1536 + bo);
    h8 MbRh = *(const h8*)(mbM + bo),        MbRl = *(const h8*)(mbM + 512 + bo);
    h8 MbIh = *(const h8*)(mbM + 1024 + bo), MbIl = *(const h8*)(mbM + 1536 + bo);
    float2 pend[4][4];
    const bool fold = (layer > 0);
    #pragma unroll
    for (int i = 0; i < 4; ++i) {
      int tile = w * 4 + i;
      int ridx;
      if (fold) {
        int oh = tile ^ (tile >> 1);
        int om = g4r ^ ((tile & 1) << 3);
        ridx = (oh << 8) | (om << 4) | (ob << 2);
      } else {
        ridx = (tile << 8) | (r << 4) | (kb << 2);
      }
      float4 ra = *(const float4*)&st[SWZA(ridx)];
      float4 rb = *(const float4*)&st[SWZA(ridx + 2)];
      float fv[8] = {ra.x, ra.y, ra.z, ra.w, rb.x, rb.y, rb.z, rb.w};
      h8 a0, a1, a2;
      #pragma unroll
      for (int j = 0; j < 8; ++j) {
        _Float16 h0, h1, h2;
        split3(fv[j], h0, h1, h2);
        a0[j] = h0; a1[j] = h1; a2[j] = h2;
      }
      f4 Lr, Li;
      cmatvec(a0, a1, a2, LbRh, LbRl, LbIh, LbIl, Lr, Li);
      // re-split L output for M (D_L frag IS M's A-frag)
      h8 b0, b1, b2;
      #pragma unroll
      for (int j = 0; j < 4; ++j) {
        _Float16 h0, h1, h2;
        split3(Lr[j], h0, h1, h2);
        b0[2*j] = h0; b1[2*j] = h1; b2[2*j] = h2;
        split3(Li[j], h0, h1, h2);
        b0[2*j+1] = h0; b1[2*j+1] = h1; b2[2*j+1] = h2;
      }
      f4 Mr, Mi;
      cmatvec(b0, b1, b2, MbRh, MbRl, MbIh, MbIl, Mr, Mi);
      #pragma unroll
      for (int j = 0; j < 4; ++j)
        pend[i][j] = make_float2(Mr[j], Mi[j]);
    }
    __syncthreads();  // all S_in reads complete
    // scatter-write S_mid [m'][l'][h]: amp = (r<<8)|((4kb+j)<<4)|tile
    #pragma unroll
    for (int i = 0; i < 4; ++i) {
      int tile = w * 4 + i;
      #pragma unroll
      for (int j = 0; j < 4; ++j) {
        int amp = (r << 8) | ((4 * kb + j) << 4) | tile;
        st[SWZA(amp)] = pend[i][j];
      }
    }
    __syncthreads();  // S_mid complete

    // ======== phase 2: H stage ========
    const _Float16* mbH = mats + (layer * 3 + 2) * 2048;
    h8 HbRh = *(const h8*)(mbH + bo),        HbRl = *(const h8*)(mbH + 512 + bo);
    h8 HbIh = *(const h8*)(mbH + 1024 + bo), HbIl = *(const h8*)(mbH + 1536 + bo);
    float4 pA[4], pB[4];
    #pragma unroll
    for (int i = 0; i < 4; ++i) {
      int tile = w * 4 + i;
      int ridx = (tile << 8) | (r << 4) | (kb << 2);
      float4 ra = *(const float4*)&st[SWZA(ridx)];
      float4 rb = *(const float4*)&st[SWZA(ridx + 2)];
      float fv[8] = {ra.x, ra.y, ra.z, ra.w, rb.x, rb.y, rb.z, rb.w};
      h8 a0, a1, a2;
      #pragma unroll
      for (int j = 0; j < 8; ++j) {
        _Float16 h0, h1, h2;
        split3(fv[j], h0, h1, h2);
        a0[j] = h0; a1[j] = h1; a2[j] = h2;
      }
      f4 Hr, Hi;
      cmatvec(a0, a1, a2, HbRh, HbRl, HbIh, HbIl, Hr, Hi);
      pA[i] = make_float4(Hr[0], Hi[0], Hr[1], Hi[1]);
      pB[i] = make_float4(Hr[2], Hi[2], Hr[3], Hi[3]);
    }
    __syncthreads();  // all S_mid reads complete
    #pragma unroll
    for (int i = 0; i < 4; ++i) {
      int tile = w * 4 + i;
      int widx = (r << 8) | (tile << 4) | (kb << 2);
      *(float4*)&st[SWZA(widx)]     = pA[i];
      *(float4*)&st[SWZA(widx + 2)] = pB[i];
    }
    __syncthreads();  // S_out complete
  }

  // ---- measurement: final CNOT folded via parity signs (r6 verbatim) ----
  float psum = 0.f, A0 = 0.f, A1 = 0.f, A2 = 0.f, A3 = 0.f;
  #pragma unroll
  for (int g = 0; g < 4; ++g) {
    int idx = w * 1024 + lane * 16 + g * 4;
    float4 ra = *(const float4*)&st[SWZA(idx)];
    float4 rb = *(const float4*)&st[SWZA(idx + 2)];
    float re_[4] = {ra.x, ra.z, rb.x, rb.z};
    float im_[4] = {ra.y, ra.w, rb.y, rb.w};
    #pragma unroll
    for (int j = 0; j < 4; ++j) {
      int tt = g * 4 + j;
      float p = re_[j] * re_[j] + im_[j] * im_[j];
      psum += p;
      A0 += (__builtin_popcount((unsigned)tt) & 1) ? -p : p;
      A1 += (__builtin_popcount((unsigned)(tt >> 1)) & 1) ? -p : p;
      A2 += (__builtin_popcount((unsigned)(tt >> 2)) & 1) ? -p : p;
      A3 += (__builtin_popcount((unsigned)(tt >> 3)) & 1) ? -p : p;
    }
  }
  float zs[12];
  {
    int u = (w << 6) | lane;
    int pu = __builtin_popcount((unsigned)u) & 1;
    zs[11] = pu ? -A0 : A0;
    zs[10] = pu ? -A1 : A1;
    zs[9]  = pu ? -A2 : A2;
    zs[8]  = pu ? -A3 : A3;
    #pragma unroll
    for (int q = 0; q <= 7; ++q) {
      int sgn = __builtin_popcount((unsigned)(u >> (7 - q))) & 1;
      zs[q] = sgn ? -psum : psum;
    }
  }
  #pragma unroll
  for (int q = 0; q < 12; ++q) {
    float v = zs[q];
    #pragma unroll
    for (int off = 1; off < 64; off <<= 1) v += __shfl_xor(v, off, 64);
    zs[q] = v;
  }
  if (lane == 0) {
    #pragma unroll
    for (int q = 0; q < 12; ++q) red[w * 12 + q] = zs[q];
  }
  __syncthreads();
  if (tid < 12) red[48 + tid] = red[tid] + red[12 + tid] + red[24 + tid] + red[36 + tid];
  __syncthreads();
  if (tid < 64) {
    float acc = bias[tid];
    #pragma unroll
    for (int q = 0; q < 12; ++q) acc = fmaf(red[48 + q], W[tid * 12 + q], acc);
    out[b * 64 + tid] = acc;
  }
}

extern "C" void kernel_launch(void* const* d_in, const int* in_sizes, int n_in,
                              void* d_out, int out_size, void* d_ws, size_t ws_size,
                              hipStream_t stream) {
  const float* x      = (const float*)d_in[0];
  const float* params = (const float*)d_in[1];
  const float* W      = (const float*)d_in[2];
  const float* bias   = (const float*)d_in[3];
  float* out = (float*)d_out;
  _Float16* mats = (_Float16*)d_ws;  // 18 * 2048 f16 = 73728 bytes

  build_mats<<<18, 256, 0, stream>>>(params, mats);
  circuit_kernel<<<BATCH, 256, 0, stream>>>(x, mats, W, bias, out);
}

// Round 10
// 564.513 us; speedup vs baseline: 1.1944x; 1.1944x over previous
//
#include <hip/hip_runtime.h>
#include <math.h>

typedef _Float16 h8 __attribute__((ext_vector_type(8)));
typedef float f4 __attribute__((ext_vector_type(4)));

#define BATCH 8192

// Swizzle on amp index (float2 units): XOR bits 3:1 with hash of upper bits.
// (validated r4/r6/r8)
#define SWZA(i) ((i) ^ (((((i) >> 4) ^ ((i) >> 7) ^ ((i) >> 10)) & 7) << 1))

// ---------------------------------------------------------------------------
// Stage matrices as MFMA B-operands, split precision (hi + lo*2^11 f16).
// r8 VERBATIM (validated): double trig shared via LDS.
// ---------------------------------------------------------------------------
__global__ void build_mats(const float* __restrict__ params, _Float16* __restrict__ ws) {
  __shared__ double tg[4][6];  // per gate j: c, sn, ca, sa, cb, sb
  int s = blockIdx.x, layer = s / 3, axis = s % 3;
  int t = threadIdx.x, n = t >> 4, col = t & 15;

  if (t < 12) {
    int j = t / 3, which = t % 3;
    int q = (axis == 0) ? (11 - j) : (axis == 1) ? (7 - j) : (3 - j);
    const float* pp = params + (layer * 12 + q) * 3;
    double phi = pp[0], th = pp[1], om = pp[2];
    if (which == 0) { tg[j][0] = cos(0.5 * th);         tg[j][1] = sin(0.5 * th); }
    if (which == 1) { tg[j][2] = cos(0.5 * (phi + om)); tg[j][3] = sin(0.5 * (phi + om)); }
    if (which == 2) { tg[j][4] = cos(0.5 * (phi - om)); tg[j][5] = sin(0.5 * (phi - om)); }
  }
  __syncthreads();

  double Er = 1.0, Ei = 0.0;
  #pragma unroll
  for (int j = 0; j < 4; ++j) {
    double c = tg[j][0], sn = tg[j][1];
    double ca = tg[j][2], sa = tg[j][3], cb = tg[j][4], sb = tg[j][5];
    int nb = (n >> j) & 1, cbit = (col >> j) & 1;
    double mr, mi;
    if (!nb) {
      if (!cbit) { mr =  ca * c;  mi = -sa * c; }
      else       { mr = -cb * sn; mi = -sb * sn; }
    } else {
      if (!cbit) { mr =  cb * sn; mi = -sb * sn; }
      else       { mr =  ca * c;  mi =  sa * c; }
    }
    double nr = Er * mr - Ei * mi, ni = Er * mi + Ei * mr;
    Er = nr; Ei = ni;
  }
  int a_;
  if (axis == 0 && layer > 0) {           // CNOT fold: Gray slot order
    int kb = col >> 2, ll = col & 3;
    a_ = kb * 4 + ((ll ^ (ll >> 1)) ^ ((kb & 1) << 1));
  } else a_ = col;
  _Float16* reh = ws + s * 2048;
  _Float16* rel = reh + 512;
  _Float16* imh = reh + 1024;
  _Float16* iml = reh + 1536;
  int o0 = n * 32 + 2 * a_, o1 = o0 + 1;
  float v; _Float16 h;
  v = (float)Er;  h = (_Float16)v; reh[o0] = h; rel[o0] = (_Float16)((v - (float)h) * 2048.f);
  v = (float)-Ei; h = (_Float16)v; reh[o1] = h; rel[o1] = (_Float16)((v - (float)h) * 2048.f);
  v = (float)Ei;  h = (_Float16)v; imh[o0] = h; iml[o0] = (_Float16)((v - (float)h) * 2048.f);
  v = (float)Er;  h = (_Float16)v; imh[o1] = h; iml[o1] = (_Float16)((v - (float)h) * 2048.f);
}

// ---- 3-way split: v = h0 + h1*2^-11 + h2*2^-22 (r8 verbatim) ----
__device__ __forceinline__ void split3(float v, _Float16& h0, _Float16& h1, _Float16& h2) {
  h0 = (_Float16)v;
  float r0 = v - (float)h0;
  h1 = (_Float16)(r0 * 2048.f);
  float r1 = r0 - (float)h1 * (1.f / 2048.f);
  h2 = (_Float16)(r1 * 4194304.f);
}

// One output part of r8's cmatvec (identical MFMA ops, order, and combine):
// main = a0*B0; corr = a1*B0 + a0*B1; corr2 = a2*B0 + a1*B1;
// out = fma(corr2, 2^-22, fma(corr, 2^-11, main)).
__device__ __forceinline__ f4 cpart(const h8& a0, const h8& a1, const h8& a2,
                                    const h8& B0, const h8& B1) {
  f4 z = {0.f, 0.f, 0.f, 0.f};
  f4 m  = __builtin_amdgcn_mfma_f32_16x16x32_f16(a0, B0, z, 0, 0, 0);
  f4 c  = __builtin_amdgcn_mfma_f32_16x16x32_f16(a1, B0, z, 0, 0, 0);
  c     = __builtin_amdgcn_mfma_f32_16x16x32_f16(a0, B1, c, 0, 0, 0);
  f4 c2 = __builtin_amdgcn_mfma_f32_16x16x32_f16(a2, B0, z, 0, 0, 0);
  c2    = __builtin_amdgcn_mfma_f32_16x16x32_f16(a1, B1, c2, 0, 0, 0);
  const float sc = 1.f / 2048.f, sc2 = 1.f / 4194304.f;
  f4 outv;
  #pragma unroll
  for (int j = 0; j < 4; ++j)
    outv[j] = fmaf(c2[j], sc2, fmaf(c[j], sc, m[j]));
  return outv;
}

// ---------------------------------------------------------------------------
// r8 numerics (f16 3-split, 10 MFMA/tile-stage) with de-spilled structure:
// phase 1 = L-loop (4 B-mats hot) then M-loop (4 B-mats hot), TR/TI parked
// in registers between. All indices/barriers/folds r4/r6/r8 verbatim.
// ---------------------------------------------------------------------------
__global__ __launch_bounds__(256) void circuit_kernel(
    const float* __restrict__ x, const _Float16* __restrict__ mats,
    const float* __restrict__ W, const float* __restrict__ bias,
    float* __restrict__ out) {
  __shared__ __align__(16) float2 st[4096];
  __shared__ float red[64];

  const int b = blockIdx.x;
  const int tid = threadIdx.x;
  const int lane = tid & 63, w = tid >> 6;
  const int r = lane & 15, kb = lane >> 4;

  // ---- init: product state of the data-encoding RY layer (r6/r8 verbatim) ----
  float cs[12], sn_[12];
  #pragma unroll
  for (int q = 0; q < 12; ++q) {
    float sv, cv;
    sincosf(0.5f * x[b * 12 + q], &sv, &cv);
    cs[11 - q] = cv; sn_[11 - q] = sv;
  }
  {
    int hb = (w << 6) | lane;
    float basep = 1.f;
    #pragma unroll
    for (int i = 0; i < 8; ++i) basep *= ((hb >> i) & 1) ? sn_[4 + i] : cs[4 + i];
    float p2[4], q2[4];
    #pragma unroll
    for (int v = 0; v < 4; ++v) {
      p2[v] = ((v & 1) ? sn_[0] : cs[0]) * ((v & 2) ? sn_[1] : cs[1]);
      q2[v] = ((v & 1) ? sn_[2] : cs[2]) * ((v & 2) ? sn_[3] : cs[3]) * basep;
    }
    #pragma unroll
    for (int g = 0; g < 4; ++g) {
      int idx = w * 1024 + lane * 16 + g * 4;
      float a0 = q2[g] * p2[0], a1 = q2[g] * p2[1];
      float a2 = q2[g] * p2[2], a3 = q2[g] * p2[3];
      *(float4*)&st[SWZA(idx)]     = make_float4(a0, 0.f, a1, 0.f);
      *(float4*)&st[SWZA(idx + 2)] = make_float4(a2, 0.f, a3, 0.f);
    }
  }
  __syncthreads();

  // fold-read constants (r4/r6/r8 verbatim)
  const int g4r = r ^ (r >> 1);
  const int kb0 = kb & 1, kb1 = kb >> 1, m0 = r & 1;
  const int ob = ((kb1 ^ m0) << 1) | (kb0 ^ kb1);
  const int bo = r * 32 + kb * 8;

  for (int layer = 0; layer < 6; ++layer) {
    f4 TR[4], TI[4];
    const bool fold = (layer > 0);
    // ---- phase 1a: L stage (fold read), only L's B-mats hot ----
    {
      const _Float16* mbL = mats + (layer * 3 + 0) * 2048;
      h8 LbRh = *(const h8*)(mbL + bo),        LbRl = *(const h8*)(mbL + 512 + bo);
      h8 LbIh = *(const h8*)(mbL + 1024 + bo), LbIl = *(const h8*)(mbL + 1536 + bo);
      #pragma unroll
      for (int i = 0; i < 4; ++i) {
        int tile = w * 4 + i;
        int ridx;
        if (fold) {
          int oh = tile ^ (tile >> 1);
          int om = g4r ^ ((tile & 1) << 3);
          ridx = (oh << 8) | (om << 4) | (ob << 2);
        } else {
          ridx = (tile << 8) | (r << 4) | (kb << 2);
        }
        float4 ra = *(const float4*)&st[SWZA(ridx)];
        float4 rb = *(const float4*)&st[SWZA(ridx + 2)];
        float fv[8] = {ra.x, ra.y, ra.z, ra.w, rb.x, rb.y, rb.z, rb.w};
        h8 a0, a1, a2;
        #pragma unroll
        for (int j = 0; j < 8; ++j) {
          _Float16 h0, h1, h2;
          split3(fv[j], h0, h1, h2);
          a0[j] = h0; a1[j] = h1; a2[j] = h2;
        }
        TR[i] = cpart(a0, a1, a2, LbRh, LbRl);
        TI[i] = cpart(a0, a1, a2, LbIh, LbIl);
      }
    }
    // ---- phase 1b: M stage from registers (D_L frag IS M's A-frag) ----
    {
      const _Float16* mbM = mats + (layer * 3 + 1) * 2048;
      h8 MbRh = *(const h8*)(mbM + bo),        MbRl = *(const h8*)(mbM + 512 + bo);
      h8 MbIh = *(const h8*)(mbM + 1024 + bo), MbIl = *(const h8*)(mbM + 1536 + bo);
      #pragma unroll
      for (int i = 0; i < 4; ++i) {
        h8 b0, b1, b2;
        #pragma unroll
        for (int j = 0; j < 4; ++j) {
          _Float16 h0, h1, h2;
          split3(TR[i][j], h0, h1, h2);
          b0[2*j] = h0; b1[2*j] = h1; b2[2*j] = h2;
          split3(TI[i][j], h0, h1, h2);
          b0[2*j+1] = h0; b1[2*j+1] = h1; b2[2*j+1] = h2;
        }
        f4 MR = cpart(b0, b1, b2, MbRh, MbRl);
        f4 MI = cpart(b0, b1, b2, MbIh, MbIl);
        TR[i] = MR; TI[i] = MI;
      }
    }
    __syncthreads();  // all S_in reads complete
    // scatter-write S_mid [m'][l'][h]: amp = (r<<8)|((4kb+j)<<4)|tile
    #pragma unroll
    for (int i = 0; i < 4; ++i) {
      int tile = w * 4 + i;
      #pragma unroll
      for (int j = 0; j < 4; ++j) {
        int amp = (r << 8) | ((4 * kb + j) << 4) | tile;
        st[SWZA(amp)] = make_float2(TR[i][j], TI[i][j]);
      }
    }
    __syncthreads();  // S_mid complete

    // ---- phase 2: H stage ----
    {
      const _Float16* mbH = mats + (layer * 3 + 2) * 2048;
      h8 HbRh = *(const h8*)(mbH + bo),        HbRl = *(const h8*)(mbH + 512 + bo);
      h8 HbIh = *(const h8*)(mbH + 1024 + bo), HbIl = *(const h8*)(mbH + 1536 + bo);
      float4 pA[4], pB[4];
      #pragma unroll
      for (int i = 0; i < 4; ++i) {
        int tile = w * 4 + i;
        int ridx = (tile << 8) | (r << 4) | (kb << 2);
        float4 ra = *(const float4*)&st[SWZA(ridx)];
        float4 rb = *(const float4*)&st[SWZA(ridx + 2)];
        float fv[8] = {ra.x, ra.y, ra.z, ra.w, rb.x, rb.y, rb.z, rb.w};
        h8 a0, a1, a2;
        #pragma unroll
        for (int j = 0; j < 8; ++j) {
          _Float16 h0, h1, h2;
          split3(fv[j], h0, h1, h2);
          a0[j] = h0; a1[j] = h1; a2[j] = h2;
        }
        f4 HR = cpart(a0, a1, a2, HbRh, HbRl);
        f4 HI = cpart(a0, a1, a2, HbIh, HbIl);
        pA[i] = make_float4(HR[0], HI[0], HR[1], HI[1]);
        pB[i] = make_float4(HR[2], HI[2], HR[3], HI[3]);
      }
      __syncthreads();  // all S_mid reads complete
      #pragma unroll
      for (int i = 0; i < 4; ++i) {
        int tile = w * 4 + i;
        int widx = (r << 8) | (tile << 4) | (kb << 2);
        *(float4*)&st[SWZA(widx)]     = pA[i];
        *(float4*)&st[SWZA(widx + 2)] = pB[i];
      }
      __syncthreads();  // S_out complete
    }
  }

  // ---- measurement: final CNOT folded via parity signs (r8 verbatim) ----
  float psum = 0.f, A0 = 0.f, A1 = 0.f, A2 = 0.f, A3 = 0.f;
  #pragma unroll
  for (int g = 0; g < 4; ++g) {
    int idx = w * 1024 + lane * 16 + g * 4;
    float4 ra = *(const float4*)&st[SWZA(idx)];
    float4 rb = *(const float4*)&st[SWZA(idx + 2)];
    float re_[4] = {ra.x, ra.z, rb.x, rb.z};
    float im_[4] = {ra.y, ra.w, rb.y, rb.w};
    #pragma unroll
    for (int j = 0; j < 4; ++j) {
      int tt = g * 4 + j;
      float p = re_[j] * re_[j] + im_[j] * im_[j];
      psum += p;
      A0 += (__builtin_popcount((unsigned)tt) & 1) ? -p : p;
      A1 += (__builtin_popcount((unsigned)(tt >> 1)) & 1) ? -p : p;
      A2 += (__builtin_popcount((unsigned)(tt >> 2)) & 1) ? -p : p;
      A3 += (__builtin_popcount((unsigned)(tt >> 3)) & 1) ? -p : p;
    }
  }
  float zs[12];
  {
    int u = (w << 6) | lane;
    int pu = __builtin_popcount((unsigned)u) & 1;
    zs[11] = pu ? -A0 : A0;
    zs[10] = pu ? -A1 : A1;
    zs[9]  = pu ? -A2 : A2;
    zs[8]  = pu ? -A3 : A3;
    #pragma unroll
    for (int q = 0; q <= 7; ++q) {
      int sgn = __builtin_popcount((unsigned)(u >> (7 - q))) & 1;
      zs[q] = sgn ? -psum : psum;
    }
  }
  #pragma unroll
  for (int q = 0; q < 12; ++q) {
    float v = zs[q];
    #pragma unroll
    for (int off = 1; off < 64; off <<= 1) v += __shfl_xor(v, off, 64);
    zs[q] = v;
  }
  if (lane == 0) {
    #pragma unroll
    for (int q = 0; q < 12; ++q) red[w * 12 + q] = zs[q];
  }
  __syncthreads();
  if (tid < 12) red[48 + tid] = red[tid] + red[12 + tid] + red[24 + tid] + red[36 + tid];
  __syncthreads();
  if (tid < 64) {
    float acc = bias[tid];
    #pragma unroll
    for (int q = 0; q < 12; ++q) acc = fmaf(red[48 + q], W[tid * 12 + q], acc);
    out[b * 64 + tid] = acc;
  }
}

extern "C" void kernel_launch(void* const* d_in, const int* in_sizes, int n_in,
                              void* d_out, int out_size, void* d_ws, size_t ws_size,
                              hipStream_t stream) {
  const float* x      = (const float*)d_in[0];
  const float* params = (const float*)d_in[1];
  const float* W      = (const float*)d_in[2];
  const float* bias   = (const float*)d_in[3];
  float* out = (float*)d_out;
  _Float16* mats = (_Float16*)d_ws;  // 18 * 2048 f16 = 73728 bytes

  build_mats<<<18, 256, 0, stream>>>(params, mats);
  circuit_kernel<<<BATCH, 256, 0, stream>>>(x, mats, W, bias, out);
}

// Round 11
// 562.897 us; speedup vs baseline: 1.1979x; 1.0029x over previous
//
#include <hip/hip_runtime.h>
#include <math.h>

typedef _Float16 h8 __attribute__((ext_vector_type(8)));
typedef float f4 __attribute__((ext_vector_type(4)));

#define BATCH 8192

// Swizzle on amp index (float2 units): XOR bits 3:1 with hash of upper bits.
// (validated r4/r6/r8)
#define SWZA(i) ((i) ^ (((((i) >> 4) ^ ((i) >> 7) ^ ((i) >> 10)) & 7) << 1))

// ---------------------------------------------------------------------------
// Stage matrices as MFMA B-operands, split precision (hi + lo*2^11 f16).
// r8 VERBATIM (validated): double trig shared via LDS.
// ---------------------------------------------------------------------------
__global__ void build_mats(const float* __restrict__ params, _Float16* __restrict__ ws) {
  __shared__ double tg[4][6];  // per gate j: c, sn, ca, sa, cb, sb
  int s = blockIdx.x, layer = s / 3, axis = s % 3;
  int t = threadIdx.x, n = t >> 4, col = t & 15;

  if (t < 12) {
    int j = t / 3, which = t % 3;
    int q = (axis == 0) ? (11 - j) : (axis == 1) ? (7 - j) : (3 - j);
    const float* pp = params + (layer * 12 + q) * 3;
    double phi = pp[0], th = pp[1], om = pp[2];
    if (which == 0) { tg[j][0] = cos(0.5 * th);         tg[j][1] = sin(0.5 * th); }
    if (which == 1) { tg[j][2] = cos(0.5 * (phi + om)); tg[j][3] = sin(0.5 * (phi + om)); }
    if (which == 2) { tg[j][4] = cos(0.5 * (phi - om)); tg[j][5] = sin(0.5 * (phi - om)); }
  }
  __syncthreads();

  double Er = 1.0, Ei = 0.0;
  #pragma unroll
  for (int j = 0; j < 4; ++j) {
    double c = tg[j][0], sn = tg[j][1];
    double ca = tg[j][2], sa = tg[j][3], cb = tg[j][4], sb = tg[j][5];
    int nb = (n >> j) & 1, cbit = (col >> j) & 1;
    double mr, mi;
    if (!nb) {
      if (!cbit) { mr =  ca * c;  mi = -sa * c; }
      else       { mr = -cb * sn; mi = -sb * sn; }
    } else {
      if (!cbit) { mr =  cb * sn; mi = -sb * sn; }
      else       { mr =  ca * c;  mi =  sa * c; }
    }
    double nr = Er * mr - Ei * mi, ni = Er * mi + Ei * mr;
    Er = nr; Ei = ni;
  }
  int a_;
  if (axis == 0 && layer > 0) {           // CNOT fold: Gray slot order
    int kb = col >> 2, ll = col & 3;
    a_ = kb * 4 + ((ll ^ (ll >> 1)) ^ ((kb & 1) << 1));
  } else a_ = col;
  _Float16* reh = ws + s * 2048;
  _Float16* rel = reh + 512;
  _Float16* imh = reh + 1024;
  _Float16* iml = reh + 1536;
  int o0 = n * 32 + 2 * a_, o1 = o0 + 1;
  float v; _Float16 h;
  v = (float)Er;  h = (_Float16)v; reh[o0] = h; rel[o0] = (_Float16)((v - (float)h) * 2048.f);
  v = (float)-Ei; h = (_Float16)v; reh[o1] = h; rel[o1] = (_Float16)((v - (float)h) * 2048.f);
  v = (float)Ei;  h = (_Float16)v; imh[o0] = h; iml[o0] = (_Float16)((v - (float)h) * 2048.f);
  v = (float)Er;  h = (_Float16)v; imh[o1] = h; iml[o1] = (_Float16)((v - (float)h) * 2048.f);
}

// ---- 3-way split: v = h0 + h1*2^-11 + h2*2^-22 (r8 verbatim) ----
__device__ __forceinline__ void split3(float v, _Float16& h0, _Float16& h1, _Float16& h2) {
  h0 = (_Float16)v;
  float r0 = v - (float)h0;
  h1 = (_Float16)(r0 * 2048.f);
  float r1 = r0 - (float)h1 * (1.f / 2048.f);
  h2 = (_Float16)(r1 * 4194304.f);
}

// One output part of r8's cmatvec (identical MFMA ops, order, and combine):
// main = a0*B0; corr = a1*B0 + a0*B1; corr2 = a2*B0 + a1*B1;
// out = fma(corr2, 2^-22, fma(corr, 2^-11, main)).
__device__ __forceinline__ f4 cpart(const h8& a0, const h8& a1, const h8& a2,
                                    const h8& B0, const h8& B1) {
  f4 z = {0.f, 0.f, 0.f, 0.f};
  f4 m  = __builtin_amdgcn_mfma_f32_16x16x32_f16(a0, B0, z, 0, 0, 0);
  f4 c  = __builtin_amdgcn_mfma_f32_16x16x32_f16(a1, B0, z, 0, 0, 0);
  c     = __builtin_amdgcn_mfma_f32_16x16x32_f16(a0, B1, c, 0, 0, 0);
  f4 c2 = __builtin_amdgcn_mfma_f32_16x16x32_f16(a2, B0, z, 0, 0, 0);
  c2    = __builtin_amdgcn_mfma_f32_16x16x32_f16(a1, B1, c2, 0, 0, 0);
  const float sc = 1.f / 2048.f, sc2 = 1.f / 4194304.f;
  f4 outv;
  #pragma unroll
  for (int j = 0; j < 4; ++j)
    outv[j] = fmaf(c2[j], sc2, fmaf(c[j], sc, m[j]));
  return outv;
}

// ---------------------------------------------------------------------------
// r8 numerics (f16 3-split, 10 MFMA/tile-stage) with de-spilled structure:
// phase 1 = L-loop (4 B-mats hot) then M-loop (4 B-mats hot), TR/TI parked
// in registers between. All indices/barriers/folds r4/r6/r8 verbatim.
// ---------------------------------------------------------------------------
__global__ __launch_bounds__(256) void circuit_kernel(
    const float* __restrict__ x, const _Float16* __restrict__ mats,
    const float* __restrict__ W, const float* __restrict__ bias,
    float* __restrict__ out) {
  __shared__ __align__(16) float2 st[4096];
  __shared__ float red[64];

  const int b = blockIdx.x;
  const int tid = threadIdx.x;
  const int lane = tid & 63, w = tid >> 6;
  const int r = lane & 15, kb = lane >> 4;

  // ---- init: product state of the data-encoding RY layer (r6/r8 verbatim) ----
  float cs[12], sn_[12];
  #pragma unroll
  for (int q = 0; q < 12; ++q) {
    float sv, cv;
    sincosf(0.5f * x[b * 12 + q], &sv, &cv);
    cs[11 - q] = cv; sn_[11 - q] = sv;
  }
  {
    int hb = (w << 6) | lane;
    float basep = 1.f;
    #pragma unroll
    for (int i = 0; i < 8; ++i) basep *= ((hb >> i) & 1) ? sn_[4 + i] : cs[4 + i];
    float p2[4], q2[4];
    #pragma unroll
    for (int v = 0; v < 4; ++v) {
      p2[v] = ((v & 1) ? sn_[0] : cs[0]) * ((v & 2) ? sn_[1] : cs[1]);
      q2[v] = ((v & 1) ? sn_[2] : cs[2]) * ((v & 2) ? sn_[3] : cs[3]) * basep;
    }
    #pragma unroll
    for (int g = 0; g < 4; ++g) {
      int idx = w * 1024 + lane * 16 + g * 4;
      float a0 = q2[g] * p2[0], a1 = q2[g] * p2[1];
      float a2 = q2[g] * p2[2], a3 = q2[g] * p2[3];
      *(float4*)&st[SWZA(idx)]     = make_float4(a0, 0.f, a1, 0.f);
      *(float4*)&st[SWZA(idx + 2)] = make_float4(a2, 0.f, a3, 0.f);
    }
  }
  __syncthreads();

  // fold-read constants (r4/r6/r8 verbatim)
  const int g4r = r ^ (r >> 1);
  const int kb0 = kb & 1, kb1 = kb >> 1, m0 = r & 1;
  const int ob = ((kb1 ^ m0) << 1) | (kb0 ^ kb1);
  const int bo = r * 32 + kb * 8;

  for (int layer = 0; layer < 6; ++layer) {
    f4 TR[4], TI[4];
    const bool fold = (layer > 0);
    // ---- phase 1a: L stage (fold read), only L's B-mats hot ----
    {
      const _Float16* mbL = mats + (layer * 3 + 0) * 2048;
      h8 LbRh = *(const h8*)(mbL + bo),        LbRl = *(const h8*)(mbL + 512 + bo);
      h8 LbIh = *(const h8*)(mbL + 1024 + bo), LbIl = *(const h8*)(mbL + 1536 + bo);
      #pragma unroll
      for (int i = 0; i < 4; ++i) {
        int tile = w * 4 + i;
        int ridx;
        if (fold) {
          int oh = tile ^ (tile >> 1);
          int om = g4r ^ ((tile & 1) << 3);
          ridx = (oh << 8) | (om << 4) | (ob << 2);
        } else {
          ridx = (tile << 8) | (r << 4) | (kb << 2);
        }
        float4 ra = *(const float4*)&st[SWZA(ridx)];
        float4 rb = *(const float4*)&st[SWZA(ridx + 2)];
        float fv[8] = {ra.x, ra.y, ra.z, ra.w, rb.x, rb.y, rb.z, rb.w};
        h8 a0, a1, a2;
        #pragma unroll
        for (int j = 0; j < 8; ++j) {
          _Float16 h0, h1, h2;
          split3(fv[j], h0, h1, h2);
          a0[j] = h0; a1[j] = h1; a2[j] = h2;
        }
        TR[i] = cpart(a0, a1, a2, LbRh, LbRl);
        TI[i] = cpart(a0, a1, a2, LbIh, LbIl);
      }
    }
    // ---- phase 1b: M stage from registers (D_L frag IS M's A-frag) ----
    {
      const _Float16* mbM = mats + (layer * 3 + 1) * 2048;
      h8 MbRh = *(const h8*)(mbM + bo),        MbRl = *(const h8*)(mbM + 512 + bo);
      h8 MbIh = *(const h8*)(mbM + 1024 + bo), MbIl = *(const h8*)(mbM + 1536 + bo);
      #pragma unroll
      for (int i = 0; i < 4; ++i) {
        h8 b0, b1, b2;
        #pragma unroll
        for (int j = 0; j < 4; ++j) {
          _Float16 h0, h1, h2;
          split3(TR[i][j], h0, h1, h2);
          b0[2*j] = h0; b1[2*j] = h1; b2[2*j] = h2;
          split3(TI[i][j], h0, h1, h2);
          b0[2*j+1] = h0; b1[2*j+1] = h1; b2[2*j+1] = h2;
        }
        f4 MR = cpart(b0, b1, b2, MbRh, MbRl);
        f4 MI = cpart(b0, b1, b2, MbIh, MbIl);
        TR[i] = MR; TI[i] = MI;
      }
    }
    __syncthreads();  // all S_in reads complete
    // scatter-write S_mid [m'][l'][h]: amp = (r<<8)|((4kb+j)<<4)|tile
    #pragma unroll
    for (int i = 0; i < 4; ++i) {
      int tile = w * 4 + i;
      #pragma unroll
      for (int j = 0; j < 4; ++j) {
        int amp = (r << 8) | ((4 * kb + j) << 4) | tile;
        st[SWZA(amp)] = make_float2(TR[i][j], TI[i][j]);
      }
    }
    __syncthreads();  // S_mid complete

    // ---- phase 2: H stage ----
    {
      const _Float16* mbH = mats + (layer * 3 + 2) * 2048;
      h8 HbRh = *(const h8*)(mbH + bo),        HbRl = *(const h8*)(mbH + 512 + bo);
      h8 HbIh = *(const h8*)(mbH + 1024 + bo), HbIl = *(const h8*)(mbH + 1536 + bo);
      float4 pA[4], pB[4];
      #pragma unroll
      for (int i = 0; i < 4; ++i) {
        int tile = w * 4 + i;
        int ridx = (tile << 8) | (r << 4) | (kb << 2);
        float4 ra = *(const float4*)&st[SWZA(ridx)];
        float4 rb = *(const float4*)&st[SWZA(ridx + 2)];
        float fv[8] = {ra.x, ra.y, ra.z, ra.w, rb.x, rb.y, rb.z, rb.w};
        h8 a0, a1, a2;
        #pragma unroll
        for (int j = 0; j < 8; ++j) {
          _Float16 h0, h1, h2;
          split3(fv[j], h0, h1, h2);
          a0[j] = h0; a1[j] = h1; a2[j] = h2;
        }
        f4 HR = cpart(a0, a1, a2, HbRh, HbRl);
        f4 HI = cpart(a0, a1, a2, HbIh, HbIl);
        pA[i] = make_float4(HR[0], HI[0], HR[1], HI[1]);
        pB[i] = make_float4(HR[2], HI[2], HR[3], HI[3]);
      }
      __syncthreads();  // all S_mid reads complete
      #pragma unroll
      for (int i = 0; i < 4; ++i) {
        int tile = w * 4 + i;
        int widx = (r << 8) | (tile << 4) | (kb << 2);
        *(float4*)&st[SWZA(widx)]     = pA[i];
        *(float4*)&st[SWZA(widx + 2)] = pB[i];
      }
      __syncthreads();  // S_out complete
    }
  }

  // ---- measurement: final CNOT folded via parity signs (r8 verbatim) ----
  float psum = 0.f, A0 = 0.f, A1 = 0.f, A2 = 0.f, A3 = 0.f;
  #pragma unroll
  for (int g = 0; g < 4; ++g) {
    int idx = w * 1024 + lane * 16 + g * 4;
    float4 ra = *(const float4*)&st[SWZA(idx)];
    float4 rb = *(const float4*)&st[SWZA(idx + 2)];
    float re_[4] = {ra.x, ra.z, rb.x, rb.z};
    float im_[4] = {ra.y, ra.w, rb.y, rb.w};
    #pragma unroll
    for (int j = 0; j < 4; ++j) {
      int tt = g * 4 + j;
      float p = re_[j] * re_[j] + im_[j] * im_[j];
      psum += p;
      A0 += (__builtin_popcount((unsigned)tt) & 1) ? -p : p;
      A1 += (__builtin_popcount((unsigned)(tt >> 1)) & 1) ? -p : p;
      A2 += (__builtin_popcount((unsigned)(tt >> 2)) & 1) ? -p : p;
      A3 += (__builtin_popcount((unsigned)(tt >> 3)) & 1) ? -p : p;
    }
  }
  float zs[12];
  {
    int u = (w << 6) | lane;
    int pu = __builtin_popcount((unsigned)u) & 1;
    zs[11] = pu ? -A0 : A0;
    zs[10] = pu ? -A1 : A1;
    zs[9]  = pu ? -A2 : A2;
    zs[8]  = pu ? -A3 : A3;
    #pragma unroll
    for (int q = 0; q <= 7; ++q) {
      int sgn = __builtin_popcount((unsigned)(u >> (7 - q))) & 1;
      zs[q] = sgn ? -psum : psum;
    }
  }
  #pragma unroll
  for (int q = 0; q < 12; ++q) {
    float v = zs[q];
    #pragma unroll
    for (int off = 1; off < 64; off <<= 1) v += __shfl_xor(v, off, 64);
    zs[q] = v;
  }
  if (lane == 0) {
    #pragma unroll
    for (int q = 0; q < 12; ++q) red[w * 12 + q] = zs[q];
  }
  __syncthreads();
  if (tid < 12) red[48 + tid] = red[tid] + red[12 + tid] + red[24 + tid] + red[36 + tid];
  __syncthreads();
  if (tid < 64) {
    float acc = bias[tid];
    #pragma unroll
    for (int q = 0; q < 12; ++q) acc = fmaf(red[48 + q], W[tid * 12 + q], acc);
    out[b * 64 + tid] = acc;
  }
}

extern "C" void kernel_launch(void* const* d_in, const int* in_sizes, int n_in,
                              void* d_out, int out_size, void* d_ws, size_t ws_size,
                              hipStream_t stream) {
  const float* x      = (const float*)d_in[0];
  const float* params = (const float*)d_in[1];
  const float* W      = (const float*)d_in[2];
  const float* bias   = (const float*)d_in[3];
  float* out = (float*)d_out;
  _Float16* mats = (_Float16*)d_ws;  // 18 * 2048 f16 = 73728 bytes

  build_mats<<<18, 256, 0, stream>>>(params, mats);
  circuit_kernel<<<BATCH, 256, 0, stream>>>(x, mats, W, bias, out);
}

// Round 12
// 510.032 us; speedup vs baseline: 1.3220x; 1.1037x over previous
//
#include <hip/hip_runtime.h>
#include <math.h>

typedef _Float16 h8 __attribute__((ext_vector_type(8)));
typedef float f4 __attribute__((ext_vector_type(4)));

#define BATCH 8192

// Swizzle on amp index (float2 units): XOR bits 3:1 with hash of upper bits.
// (validated r4/r6/r8/r10)
#define SWZA(i) ((i) ^ (((((i) >> 4) ^ ((i) >> 7) ^ ((i) >> 10)) & 7) << 1))

// ---------------------------------------------------------------------------
// Stage matrices as MFMA B-operands, split precision (hi + lo*2^11 f16).
// r8/r10 VERBATIM (validated): double trig shared via LDS.
// ---------------------------------------------------------------------------
__global__ void build_mats(const float* __restrict__ params, _Float16* __restrict__ ws) {
  __shared__ double tg[4][6];  // per gate j: c, sn, ca, sa, cb, sb
  int s = blockIdx.x, layer = s / 3, axis = s % 3;
  int t = threadIdx.x, n = t >> 4, col = t & 15;

  if (t < 12) {
    int j = t / 3, which = t % 3;
    int q = (axis == 0) ? (11 - j) : (axis == 1) ? (7 - j) : (3 - j);
    const float* pp = params + (layer * 12 + q) * 3;
    double phi = pp[0], th = pp[1], om = pp[2];
    if (which == 0) { tg[j][0] = cos(0.5 * th);         tg[j][1] = sin(0.5 * th); }
    if (which == 1) { tg[j][2] = cos(0.5 * (phi + om)); tg[j][3] = sin(0.5 * (phi + om)); }
    if (which == 2) { tg[j][4] = cos(0.5 * (phi - om)); tg[j][5] = sin(0.5 * (phi - om)); }
  }
  __syncthreads();

  double Er = 1.0, Ei = 0.0;
  #pragma unroll
  for (int j = 0; j < 4; ++j) {
    double c = tg[j][0], sn = tg[j][1];
    double ca = tg[j][2], sa = tg[j][3], cb = tg[j][4], sb = tg[j][5];
    int nb = (n >> j) & 1, cbit = (col >> j) & 1;
    double mr, mi;
    if (!nb) {
      if (!cbit) { mr =  ca * c;  mi = -sa * c; }
      else       { mr = -cb * sn; mi = -sb * sn; }
    } else {
      if (!cbit) { mr =  cb * sn; mi = -sb * sn; }
      else       { mr =  ca * c;  mi =  sa * c; }
    }
    double nr = Er * mr - Ei * mi, ni = Er * mi + Ei * mr;
    Er = nr; Ei = ni;
  }
  int a_;
  if (axis == 0 && layer > 0) {           // CNOT fold: Gray slot order
    int kb = col >> 2, ll = col & 3;
    a_ = kb * 4 + ((ll ^ (ll >> 1)) ^ ((kb & 1) << 1));
  } else a_ = col;
  _Float16* reh = ws + s * 2048;
  _Float16* rel = reh + 512;
  _Float16* imh = reh + 1024;
  _Float16* iml = reh + 1536;
  int o0 = n * 32 + 2 * a_, o1 = o0 + 1;
  float v; _Float16 h;
  v = (float)Er;  h = (_Float16)v; reh[o0] = h; rel[o0] = (_Float16)((v - (float)h) * 2048.f);
  v = (float)-Ei; h = (_Float16)v; reh[o1] = h; rel[o1] = (_Float16)((v - (float)h) * 2048.f);
  v = (float)Ei;  h = (_Float16)v; imh[o0] = h; iml[o0] = (_Float16)((v - (float)h) * 2048.f);
  v = (float)Er;  h = (_Float16)v; imh[o1] = h; iml[o1] = (_Float16)((v - (float)h) * 2048.f);
}

// ---- 3-way split: v = h0 + h1*2^-11 + h2*2^-22 (r8/r10 verbatim) ----
__device__ __forceinline__ void split3(float v, _Float16& h0, _Float16& h1, _Float16& h2) {
  h0 = (_Float16)v;
  float r0 = v - (float)h0;
  h1 = (_Float16)(r0 * 2048.f);
  float r1 = r0 - (float)h1 * (1.f / 2048.f);
  h2 = (_Float16)(r1 * 4194304.f);
}

// One output part (r8/r10 verbatim MFMA ops, order, combine).
__device__ __forceinline__ f4 cpart(const h8& a0, const h8& a1, const h8& a2,
                                    const h8& B0, const h8& B1) {
  f4 z = {0.f, 0.f, 0.f, 0.f};
  f4 m  = __builtin_amdgcn_mfma_f32_16x16x32_f16(a0, B0, z, 0, 0, 0);
  f4 c  = __builtin_amdgcn_mfma_f32_16x16x32_f16(a1, B0, z, 0, 0, 0);
  c     = __builtin_amdgcn_mfma_f32_16x16x32_f16(a0, B1, c, 0, 0, 0);
  f4 c2 = __builtin_amdgcn_mfma_f32_16x16x32_f16(a2, B0, z, 0, 0, 0);
  c2    = __builtin_amdgcn_mfma_f32_16x16x32_f16(a1, B1, c2, 0, 0, 0);
  const float sc = 1.f / 2048.f, sc2 = 1.f / 4194304.f;
  f4 outv;
  #pragma unroll
  for (int j = 0; j < 4; ++j)
    outv[j] = fmaf(c2[j], sc2, fmaf(c[j], sc, m[j]));
  return outv;
}

// ---------------------------------------------------------------------------
// r10 VERBATIM except __launch_bounds__(256, 3): cap unified VGPR+AGPR at
// ~170/wave -> 3 waves/EU (12 waves/CU) instead of the allocator's 2-block
// choice. Peak liveness of the sequenced L->M structure (~140) fits.
// ---------------------------------------------------------------------------
__global__ __launch_bounds__(256, 3) void circuit_kernel(
    const float* __restrict__ x, const _Float16* __restrict__ mats,
    const float* __restrict__ W, const float* __restrict__ bias,
    float* __restrict__ out) {
  __shared__ __align__(16) float2 st[4096];
  __shared__ float red[64];

  const int b = blockIdx.x;
  const int tid = threadIdx.x;
  const int lane = tid & 63, w = tid >> 6;
  const int r = lane & 15, kb = lane >> 4;

  // ---- init: product state of the data-encoding RY layer ----
  float cs[12], sn_[12];
  #pragma unroll
  for (int q = 0; q < 12; ++q) {
    float sv, cv;
    sincosf(0.5f * x[b * 12 + q], &sv, &cv);
    cs[11 - q] = cv; sn_[11 - q] = sv;
  }
  {
    int hb = (w << 6) | lane;
    float basep = 1.f;
    #pragma unroll
    for (int i = 0; i < 8; ++i) basep *= ((hb >> i) & 1) ? sn_[4 + i] : cs[4 + i];
    float p2[4], q2[4];
    #pragma unroll
    for (int v = 0; v < 4; ++v) {
      p2[v] = ((v & 1) ? sn_[0] : cs[0]) * ((v & 2) ? sn_[1] : cs[1]);
      q2[v] = ((v & 1) ? sn_[2] : cs[2]) * ((v & 2) ? sn_[3] : cs[3]) * basep;
    }
    #pragma unroll
    for (int g = 0; g < 4; ++g) {
      int idx = w * 1024 + lane * 16 + g * 4;
      float a0 = q2[g] * p2[0], a1 = q2[g] * p2[1];
      float a2 = q2[g] * p2[2], a3 = q2[g] * p2[3];
      *(float4*)&st[SWZA(idx)]     = make_float4(a0, 0.f, a1, 0.f);
      *(float4*)&st[SWZA(idx + 2)] = make_float4(a2, 0.f, a3, 0.f);
    }
  }
  __syncthreads();

  // fold-read constants (r4/r6/r8/r10 verbatim)
  const int g4r = r ^ (r >> 1);
  const int kb0 = kb & 1, kb1 = kb >> 1, m0 = r & 1;
  const int ob = ((kb1 ^ m0) << 1) | (kb0 ^ kb1);
  const int bo = r * 32 + kb * 8;

  for (int layer = 0; layer < 6; ++layer) {
    f4 TR[4], TI[4];
    const bool fold = (layer > 0);
    // ---- phase 1a: L stage (fold read), only L's B-mats hot ----
    {
      const _Float16* mbL = mats + (layer * 3 + 0) * 2048;
      h8 LbRh = *(const h8*)(mbL + bo),        LbRl = *(const h8*)(mbL + 512 + bo);
      h8 LbIh = *(const h8*)(mbL + 1024 + bo), LbIl = *(const h8*)(mbL + 1536 + bo);
      #pragma unroll
      for (int i = 0; i < 4; ++i) {
        int tile = w * 4 + i;
        int ridx;
        if (fold) {
          int oh = tile ^ (tile >> 1);
          int om = g4r ^ ((tile & 1) << 3);
          ridx = (oh << 8) | (om << 4) | (ob << 2);
        } else {
          ridx = (tile << 8) | (r << 4) | (kb << 2);
        }
        float4 ra = *(const float4*)&st[SWZA(ridx)];
        float4 rb = *(const float4*)&st[SWZA(ridx + 2)];
        float fv[8] = {ra.x, ra.y, ra.z, ra.w, rb.x, rb.y, rb.z, rb.w};
        h8 a0, a1, a2;
        #pragma unroll
        for (int j = 0; j < 8; ++j) {
          _Float16 h0, h1, h2;
          split3(fv[j], h0, h1, h2);
          a0[j] = h0; a1[j] = h1; a2[j] = h2;
        }
        TR[i] = cpart(a0, a1, a2, LbRh, LbRl);
        TI[i] = cpart(a0, a1, a2, LbIh, LbIl);
      }
    }
    // ---- phase 1b: M stage from registers (D_L frag IS M's A-frag) ----
    {
      const _Float16* mbM = mats + (layer * 3 + 1) * 2048;
      h8 MbRh = *(const h8*)(mbM + bo),        MbRl = *(const h8*)(mbM + 512 + bo);
      h8 MbIh = *(const h8*)(mbM + 1024 + bo), MbIl = *(const h8*)(mbM + 1536 + bo);
      #pragma unroll
      for (int i = 0; i < 4; ++i) {
        h8 b0, b1, b2;
        #pragma unroll
        for (int j = 0; j < 4; ++j) {
          _Float16 h0, h1, h2;
          split3(TR[i][j], h0, h1, h2);
          b0[2*j] = h0; b1[2*j] = h1; b2[2*j] = h2;
          split3(TI[i][j], h0, h1, h2);
          b0[2*j+1] = h0; b1[2*j+1] = h1; b2[2*j+1] = h2;
        }
        f4 MR = cpart(b0, b1, b2, MbRh, MbRl);
        f4 MI = cpart(b0, b1, b2, MbIh, MbIl);
        TR[i] = MR; TI[i] = MI;
      }
    }
    __syncthreads();  // all S_in reads complete
    // scatter-write S_mid [m'][l'][h]: amp = (r<<8)|((4kb+j)<<4)|tile
    #pragma unroll
    for (int i = 0; i < 4; ++i) {
      int tile = w * 4 + i;
      #pragma unroll
      for (int j = 0; j < 4; ++j) {
        int amp = (r << 8) | ((4 * kb + j) << 4) | tile;
        st[SWZA(amp)] = make_float2(TR[i][j], TI[i][j]);
      }
    }
    __syncthreads();  // S_mid complete

    // ---- phase 2: H stage ----
    {
      const _Float16* mbH = mats + (layer * 3 + 2) * 2048;
      h8 HbRh = *(const h8*)(mbH + bo),        HbRl = *(const h8*)(mbH + 512 + bo);
      h8 HbIh = *(const h8*)(mbH + 1024 + bo), HbIl = *(const h8*)(mbH + 1536 + bo);
      float4 pA[4], pB[4];
      #pragma unroll
      for (int i = 0; i < 4; ++i) {
        int tile = w * 4 + i;
        int ridx = (tile << 8) | (r << 4) | (kb << 2);
        float4 ra = *(const float4*)&st[SWZA(ridx)];
        float4 rb = *(const float4*)&st[SWZA(ridx + 2)];
        float fv[8] = {ra.x, ra.y, ra.z, ra.w, rb.x, rb.y, rb.z, rb.w};
        h8 a0, a1, a2;
        #pragma unroll
        for (int j = 0; j < 8; ++j) {
          _Float16 h0, h1, h2;
          split3(fv[j], h0, h1, h2);
          a0[j] = h0; a1[j] = h1; a2[j] = h2;
        }
        f4 HR = cpart(a0, a1, a2, HbRh, HbRl);
        f4 HI = cpart(a0, a1, a2, HbIh, HbIl);
        pA[i] = make_float4(HR[0], HI[0], HR[1], HI[1]);
        pB[i] = make_float4(HR[2], HI[2], HR[3], HI[3]);
      }
      __syncthreads();  // all S_mid reads complete
      #pragma unroll
      for (int i = 0; i < 4; ++i) {
        int tile = w * 4 + i;
        int widx = (r << 8) | (tile << 4) | (kb << 2);
        *(float4*)&st[SWZA(widx)]     = pA[i];
        *(float4*)&st[SWZA(widx + 2)] = pB[i];
      }
      __syncthreads();  // S_out complete
    }
  }

  // ---- measurement: final CNOT folded via parity signs (r8/r10 verbatim) ----
  float psum = 0.f, A0 = 0.f, A1 = 0.f, A2 = 0.f, A3 = 0.f;
  #pragma unroll
  for (int g = 0; g < 4; ++g) {
    int idx = w * 1024 + lane * 16 + g * 4;
    float4 ra = *(const float4*)&st[SWZA(idx)];
    float4 rb = *(const float4*)&st[SWZA(idx + 2)];
    float re_[4] = {ra.x, ra.z, rb.x, rb.z};
    float im_[4] = {ra.y, ra.w, rb.y, rb.w};
    #pragma unroll
    for (int j = 0; j < 4; ++j) {
      int tt = g * 4 + j;
      float p = re_[j] * re_[j] + im_[j] * im_[j];
      psum += p;
      A0 += (__builtin_popcount((unsigned)tt) & 1) ? -p : p;
      A1 += (__builtin_popcount((unsigned)(tt >> 1)) & 1) ? -p : p;
      A2 += (__builtin_popcount((unsigned)(tt >> 2)) & 1) ? -p : p;
      A3 += (__builtin_popcount((unsigned)(tt >> 3)) & 1) ? -p : p;
    }
  }
  float zs[12];
  {
    int u = (w << 6) | lane;
    int pu = __builtin_popcount((unsigned)u) & 1;
    zs[11] = pu ? -A0 : A0;
    zs[10] = pu ? -A1 : A1;
    zs[9]  = pu ? -A2 : A2;
    zs[8]  = pu ? -A3 : A3;
    #pragma unroll
    for (int q = 0; q <= 7; ++q) {
      int sgn = __builtin_popcount((unsigned)(u >> (7 - q))) & 1;
      zs[q] = sgn ? -psum : psum;
    }
  }
  #pragma unroll
  for (int q = 0; q < 12; ++q) {
    float v = zs[q];
    #pragma unroll
    for (int off = 1; off < 64; off <<= 1) v += __shfl_xor(v, off, 64);
    zs[q] = v;
  }
  if (lane == 0) {
    #pragma unroll
    for (int q = 0; q < 12; ++q) red[w * 12 + q] = zs[q];
  }
  __syncthreads();
  if (tid < 12) red[48 + tid] = red[tid] + red[12 + tid] + red[24 + tid] + red[36 + tid];
  __syncthreads();
  if (tid < 64) {
    float acc = bias[tid];
    #pragma unroll
    for (int q = 0; q < 12; ++q) acc = fmaf(red[48 + q], W[tid * 12 + q], acc);
    out[b * 64 + tid] = acc;
  }
}

extern "C" void kernel_launch(void* const* d_in, const int* in_sizes, int n_in,
                              void* d_out, int out_size, void* d_ws, size_t ws_size,
                              hipStream_t stream) {
  const float* x      = (const float*)d_in[0];
  const float* params = (const float*)d_in[1];
  const float* W      = (const float*)d_in[2];
  const float* bias   = (const float*)d_in[3];
  float* out = (float*)d_out;
  _Float16* mats = (_Float16*)d_ws;  // 18 * 2048 f16 = 73728 bytes

  build_mats<<<18, 256, 0, stream>>>(params, mats);
  circuit_kernel<<<BATCH, 256, 0, stream>>>(x, mats, W, bias, out);
}

// Round 14
// 460.179 us; speedup vs baseline: 1.4652x; 1.1083x over previous
//
#include <hip/hip_runtime.h>
#include <math.h>

typedef _Float16 h8 __attribute__((ext_vector_type(8)));
typedef _Float16 h2v __attribute__((ext_vector_type(2)));
typedef __fp16 fp16x2 __attribute__((ext_vector_type(2)));
typedef float f4 __attribute__((ext_vector_type(4)));
typedef unsigned int u32;

#define BATCH 8192

// Swizzle on amp index (float2 units): XOR bits 3:1 with hash of upper bits.
// (validated r4/r6/r8/r10/r12)
#define SWZA(i) ((i) ^ (((((i) >> 4) ^ ((i) >> 7) ^ ((i) >> 10)) & 7) << 1))

// ---------------------------------------------------------------------------
// Stage matrices as MFMA B-operands, split precision (hi + lo*2^11 f16).
// r8/r10/r12 VERBATIM (validated): double trig shared via LDS.
// ---------------------------------------------------------------------------
__global__ void build_mats(const float* __restrict__ params, _Float16* __restrict__ ws) {
  __shared__ double tg[4][6];  // per gate j: c, sn, ca, sa, cb, sb
  int s = blockIdx.x, layer = s / 3, axis = s % 3;
  int t = threadIdx.x, n = t >> 4, col = t & 15;

  if (t < 12) {
    int j = t / 3, which = t % 3;
    int q = (axis == 0) ? (11 - j) : (axis == 1) ? (7 - j) : (3 - j);
    const float* pp = params + (layer * 12 + q) * 3;
    double phi = pp[0], th = pp[1], om = pp[2];
    if (which == 0) { tg[j][0] = cos(0.5 * th);         tg[j][1] = sin(0.5 * th); }
    if (which == 1) { tg[j][2] = cos(0.5 * (phi + om)); tg[j][3] = sin(0.5 * (phi + om)); }
    if (which == 2) { tg[j][4] = cos(0.5 * (phi - om)); tg[j][5] = sin(0.5 * (phi - om)); }
  }
  __syncthreads();

  double Er = 1.0, Ei = 0.0;
  #pragma unroll
  for (int j = 0; j < 4; ++j) {
    double c = tg[j][0], sn = tg[j][1];
    double ca = tg[j][2], sa = tg[j][3], cb = tg[j][4], sb = tg[j][5];
    int nb = (n >> j) & 1, cbit = (col >> j) & 1;
    double mr, mi;
    if (!nb) {
      if (!cbit) { mr =  ca * c;  mi = -sa * c; }
      else       { mr = -cb * sn; mi = -sb * sn; }
    } else {
      if (!cbit) { mr =  cb * sn; mi = -sb * sn; }
      else       { mr =  ca * c;  mi =  sa * c; }
    }
    double nr = Er * mr - Ei * mi, ni = Er * mi + Ei * mr;
    Er = nr; Ei = ni;
  }
  int a_;
  if (axis == 0 && layer > 0) {           // CNOT fold: Gray slot order
    int kb = col >> 2, ll = col & 3;
    a_ = kb * 4 + ((ll ^ (ll >> 1)) ^ ((kb & 1) << 1));
  } else a_ = col;
  _Float16* reh = ws + s * 2048;
  _Float16* rel = reh + 512;
  _Float16* imh = reh + 1024;
  _Float16* iml = reh + 1536;
  int o0 = n * 32 + 2 * a_, o1 = o0 + 1;
  float v; _Float16 h;
  v = (float)Er;  h = (_Float16)v; reh[o0] = h; rel[o0] = (_Float16)((v - (float)h) * 2048.f);
  v = (float)-Ei; h = (_Float16)v; reh[o1] = h; rel[o1] = (_Float16)((v - (float)h) * 2048.f);
  v = (float)Ei;  h = (_Float16)v; imh[o0] = h; iml[o0] = (_Float16)((v - (float)h) * 2048.f);
  v = (float)Er;  h = (_Float16)v; imh[o1] = h; iml[o1] = (_Float16)((v - (float)h) * 2048.f);
}

// ---- paired RTZ 3-way split via v_cvt_pkrtz: v = h0 + h1*2^-11 + h2*2^-22.
// Residuals are Sterbenz-exact; captured precision identical to r12's RNE
// split (33 bits); results arrive pre-packed (no v_pack ops).
__device__ __forceinline__ void split3pk(float v0, float v1, u32& w0, u32& w1, u32& w2) {
  h2v p0 = __builtin_bit_cast(h2v, __builtin_amdgcn_cvt_pkrtz(v0, v1));
  float r0a = v0 - (float)p0[0];
  float r0b = v1 - (float)p0[1];
  h2v p1 = __builtin_bit_cast(h2v, __builtin_amdgcn_cvt_pkrtz(r0a * 2048.f, r0b * 2048.f));
  float r1a = r0a - (float)p1[0] * (1.f / 2048.f);
  float r1b = r0b - (float)p1[1] * (1.f / 2048.f);
  h2v p2 = __builtin_bit_cast(h2v, __builtin_amdgcn_cvt_pkrtz(r1a * 4194304.f, r1b * 4194304.f));
  w0 = __builtin_bit_cast(u32, p0);
  w1 = __builtin_bit_cast(u32, p1);
  w2 = __builtin_bit_cast(u32, p2);
}

__device__ __forceinline__ void split3x8pk(const float4& ra, const float4& rb,
                                           h8& a0, h8& a1, h8& a2) {
  uint4 w0, w1, w2;
  split3pk(ra.x, ra.y, w0.x, w1.x, w2.x);
  split3pk(ra.z, ra.w, w0.y, w1.y, w2.y);
  split3pk(rb.x, rb.y, w0.z, w1.z, w2.z);
  split3pk(rb.z, rb.w, w0.w, w1.w, w2.w);
  a0 = __builtin_bit_cast(h8, w0);
  a1 = __builtin_bit_cast(h8, w1);
  a2 = __builtin_bit_cast(h8, w2);
}

// One output part (r8/r10/r12 verbatim MFMA ops, order, combine).
__device__ __forceinline__ f4 cpart(const h8& a0, const h8& a1, const h8& a2,
                                    const h8& B0, const h8& B1) {
  f4 z = {0.f, 0.f, 0.f, 0.f};
  f4 m  = __builtin_amdgcn_mfma_f32_16x16x32_f16(a0, B0, z, 0, 0, 0);
  f4 c  = __builtin_amdgcn_mfma_f32_16x16x32_f16(a1, B0, z, 0, 0, 0);
  c     = __builtin_amdgcn_mfma_f32_16x16x32_f16(a0, B1, c, 0, 0, 0);
  f4 c2 = __builtin_amdgcn_mfma_f32_16x16x32_f16(a2, B0, z, 0, 0, 0);
  c2    = __builtin_amdgcn_mfma_f32_16x16x32_f16(a1, B1, c2, 0, 0, 0);
  const float sc = 1.f / 2048.f, sc2 = 1.f / 4194304.f;
  f4 outv;
  #pragma unroll
  for (int j = 0; j < 4; ++j)
    outv[j] = fmaf(c2[j], sc2, fmaf(c[j], sc, m[j]));
  return outv;
}

// ---------------------------------------------------------------------------
// r12 VERBATIM structure ((256,3), fused L->M + H per layer, CNOT folds);
// only the split implementation changed (split3 -> split3pk).
// ---------------------------------------------------------------------------
__global__ __launch_bounds__(256, 3) void circuit_kernel(
    const float* __restrict__ x, const _Float16* __restrict__ mats,
    const float* __restrict__ W, const float* __restrict__ bias,
    float* __restrict__ out) {
  __shared__ __align__(16) float2 st[4096];
  __shared__ float red[64];

  const int b = blockIdx.x;
  const int tid = threadIdx.x;
  const int lane = tid & 63, w = tid >> 6;
  const int r = lane & 15, kb = lane >> 4;

  // ---- init: product state of the data-encoding RY layer ----
  float cs[12], sn_[12];
  #pragma unroll
  for (int q = 0; q < 12; ++q) {
    float sv, cv;
    sincosf(0.5f * x[b * 12 + q], &sv, &cv);
    cs[11 - q] = cv; sn_[11 - q] = sv;
  }
  {
    int hb = (w << 6) | lane;
    float basep = 1.f;
    #pragma unroll
    for (int i = 0; i < 8; ++i) basep *= ((hb >> i) & 1) ? sn_[4 + i] : cs[4 + i];
    float p2[4], q2[4];
    #pragma unroll
    for (int v = 0; v < 4; ++v) {
      p2[v] = ((v & 1) ? sn_[0] : cs[0]) * ((v & 2) ? sn_[1] : cs[1]);
      q2[v] = ((v & 1) ? sn_[2] : cs[2]) * ((v & 2) ? sn_[3] : cs[3]) * basep;
    }
    #pragma unroll
    for (int g = 0; g < 4; ++g) {
      int idx = w * 1024 + lane * 16 + g * 4;
      float a0 = q2[g] * p2[0], a1 = q2[g] * p2[1];
      float a2 = q2[g] * p2[2], a3 = q2[g] * p2[3];
      *(float4*)&st[SWZA(idx)]     = make_float4(a0, 0.f, a1, 0.f);
      *(float4*)&st[SWZA(idx + 2)] = make_float4(a2, 0.f, a3, 0.f);
    }
  }
  __syncthreads();

  // fold-read constants (r4/r6/r8/r10/r12 verbatim)
  const int g4r = r ^ (r >> 1);
  const int kb0 = kb & 1, kb1 = kb >> 1, m0 = r & 1;
  const int ob = ((kb1 ^ m0) << 1) | (kb0 ^ kb1);
  const int bo = r * 32 + kb * 8;

  for (int layer = 0; layer < 6; ++layer) {
    f4 TR[4], TI[4];
    const bool fold = (layer > 0);
    // ---- phase 1a: L stage (fold read), only L's B-mats hot ----
    {
      const _Float16* mbL = mats + (layer * 3 + 0) * 2048;
      h8 LbRh = *(const h8*)(mbL + bo),        LbRl = *(const h8*)(mbL + 512 + bo);
      h8 LbIh = *(const h8*)(mbL + 1024 + bo), LbIl = *(const h8*)(mbL + 1536 + bo);
      #pragma unroll
      for (int i = 0; i < 4; ++i) {
        int tile = w * 4 + i;
        int ridx;
        if (fold) {
          int oh = tile ^ (tile >> 1);
          int om = g4r ^ ((tile & 1) << 3);
          ridx = (oh << 8) | (om << 4) | (ob << 2);
        } else {
          ridx = (tile << 8) | (r << 4) | (kb << 2);
        }
        float4 ra = *(const float4*)&st[SWZA(ridx)];
        float4 rb = *(const float4*)&st[SWZA(ridx + 2)];
        h8 a0, a1, a2;
        split3x8pk(ra, rb, a0, a1, a2);
        TR[i] = cpart(a0, a1, a2, LbRh, LbRl);
        TI[i] = cpart(a0, a1, a2, LbIh, LbIl);
      }
    }
    // ---- phase 1b: M stage from registers (D_L frag IS M's A-frag) ----
    {
      const _Float16* mbM = mats + (layer * 3 + 1) * 2048;
      h8 MbRh = *(const h8*)(mbM + bo),        MbRl = *(const h8*)(mbM + 512 + bo);
      h8 MbIh = *(const h8*)(mbM + 1024 + bo), MbIl = *(const h8*)(mbM + 1536 + bo);
      #pragma unroll
      for (int i = 0; i < 4; ++i) {
        uint4 w0, w1, w2;
        split3pk(TR[i][0], TI[i][0], w0.x, w1.x, w2.x);
        split3pk(TR[i][1], TI[i][1], w0.y, w1.y, w2.y);
        split3pk(TR[i][2], TI[i][2], w0.z, w1.z, w2.z);
        split3pk(TR[i][3], TI[i][3], w0.w, w1.w, w2.w);
        h8 b0 = __builtin_bit_cast(h8, w0);
        h8 b1 = __builtin_bit_cast(h8, w1);
        h8 b2 = __builtin_bit_cast(h8, w2);
        f4 MR = cpart(b0, b1, b2, MbRh, MbRl);
        f4 MI = cpart(b0, b1, b2, MbIh, MbIl);
        TR[i] = MR; TI[i] = MI;
      }
    }
    __syncthreads();  // all S_in reads complete
    // scatter-write S_mid [m'][l'][h]: amp = (r<<8)|((4kb+j)<<4)|tile
    #pragma unroll
    for (int i = 0; i < 4; ++i) {
      int tile = w * 4 + i;
      #pragma unroll
      for (int j = 0; j < 4; ++j) {
        int amp = (r << 8) | ((4 * kb + j) << 4) | tile;
        st[SWZA(amp)] = make_float2(TR[i][j], TI[i][j]);
      }
    }
    __syncthreads();  // S_mid complete

    // ---- phase 2: H stage ----
    {
      const _Float16* mbH = mats + (layer * 3 + 2) * 2048;
      h8 HbRh = *(const h8*)(mbH + bo),        HbRl = *(const h8*)(mbH + 512 + bo);
      h8 HbIh = *(const h8*)(mbH + 1024 + bo), HbIl = *(const h8*)(mbH + 1536 + bo);
      float4 pA[4], pB[4];
      #pragma unroll
      for (int i = 0; i < 4; ++i) {
        int tile = w * 4 + i;
        int ridx = (tile << 8) | (r << 4) | (kb << 2);
        float4 ra = *(const float4*)&st[SWZA(ridx)];
        float4 rb = *(const float4*)&st[SWZA(ridx + 2)];
        h8 a0, a1, a2;
        split3x8pk(ra, rb, a0, a1, a2);
        f4 HR = cpart(a0, a1, a2, HbRh, HbRl);
        f4 HI = cpart(a0, a1, a2, HbIh, HbIl);
        pA[i] = make_float4(HR[0], HI[0], HR[1], HI[1]);
        pB[i] = make_float4(HR[2], HI[2], HR[3], HI[3]);
      }
      __syncthreads();  // all S_mid reads complete
      #pragma unroll
      for (int i = 0; i < 4; ++i) {
        int tile = w * 4 + i;
        int widx = (r << 8) | (tile << 4) | (kb << 2);
        *(float4*)&st[SWZA(widx)]     = pA[i];
        *(float4*)&st[SWZA(widx + 2)] = pB[i];
      }
      __syncthreads();  // S_out complete
    }
  }

  // ---- measurement: final CNOT folded via parity signs (r8/r10/r12 verbatim) ----
  float psum = 0.f, A0 = 0.f, A1 = 0.f, A2 = 0.f, A3 = 0.f;
  #pragma unroll
  for (int g = 0; g < 4; ++g) {
    int idx = w * 1024 + lane * 16 + g * 4;
    float4 ra = *(const float4*)&st[SWZA(idx)];
    float4 rb = *(const float4*)&st[SWZA(idx + 2)];
    float re_[4] = {ra.x, ra.z, rb.x, rb.z};
    float im_[4] = {ra.y, ra.w, rb.y, rb.w};
    #pragma unroll
    for (int j = 0; j < 4; ++j) {
      int tt = g * 4 + j;
      float p = re_[j] * re_[j] + im_[j] * im_[j];
      psum += p;
      A0 += (__builtin_popcount((unsigned)tt) & 1) ? -p : p;
      A1 += (__builtin_popcount((unsigned)(tt >> 1)) & 1) ? -p : p;
      A2 += (__builtin_popcount((unsigned)(tt >> 2)) & 1) ? -p : p;
      A3 += (__builtin_popcount((unsigned)(tt >> 3)) & 1) ? -p : p;
    }
  }
  float zs[12];
  {
    int u = (w << 6) | lane;
    int pu = __builtin_popcount((unsigned)u) & 1;
    zs[11] = pu ? -A0 : A0;
    zs[10] = pu ? -A1 : A1;
    zs[9]  = pu ? -A2 : A2;
    zs[8]  = pu ? -A3 : A3;
    #pragma unroll
    for (int q = 0; q <= 7; ++q) {
      int sgn = __builtin_popcount((unsigned)(u >> (7 - q))) & 1;
      zs[q] = sgn ? -psum : psum;
    }
  }
  #pragma unroll
  for (int q = 0; q < 12; ++q) {
    float v = zs[q];
    #pragma unroll
    for (int off = 1; off < 64; off <<= 1) v += __shfl_xor(v, off, 64);
    zs[q] = v;
  }
  if (lane == 0) {
    #pragma unroll
    for (int q = 0; q < 12; ++q) red[w * 12 + q] = zs[q];
  }
  __syncthreads();
  if (tid < 12) red[48 + tid] = red[tid] + red[12 + tid] + red[24 + tid] + red[36 + tid];
  __syncthreads();
  if (tid < 64) {
    float acc = bias[tid];
    #pragma unroll
    for (int q = 0; q < 12; ++q) acc = fmaf(red[48 + q], W[tid * 12 + q], acc);
    out[b * 64 + tid] = acc;
  }
}

extern "C" void kernel_launch(void* const* d_in, const int* in_sizes, int n_in,
                              void* d_out, int out_size, void* d_ws, size_t ws_size,
                              hipStream_t stream) {
  const float* x      = (const float*)d_in[0];
  const float* params = (const float*)d_in[1];
  const float* W      = (const float*)d_in[2];
  const float* bias   = (const float*)d_in[3];
  float* out = (float*)d_out;
  _Float16* mats = (_Float16*)d_ws;  // 18 * 2048 f16 = 73728 bytes

  build_mats<<<18, 256, 0, stream>>>(params, mats);
  circuit_kernel<<<BATCH, 256, 0, stream>>>(x, mats, W, bias, out);
}

// Round 15
// 459.709 us; speedup vs baseline: 1.4667x; 1.0010x over previous
//
#include <hip/hip_runtime.h>
#include <math.h>

typedef _Float16 h8 __attribute__((ext_vector_type(8)));
typedef _Float16 h2v __attribute__((ext_vector_type(2)));
typedef float f4 __attribute__((ext_vector_type(4)));
typedef unsigned int u32;

#define BATCH 8192

// Swizzle on amp index (float2 units): XOR bits 3:1 with hash of upper bits.
// (validated r4/r6/r8/r10/r12/r14)
#define SWZA(i) ((i) ^ (((((i) >> 4) ^ ((i) >> 7) ^ ((i) >> 10)) & 7) << 1))

// ---------------------------------------------------------------------------
// Stage matrices as MFMA B-operands, split precision (hi + lo*2^11 f16).
// r8/r10/r12/r14 VERBATIM (validated): double trig shared via LDS.
// ---------------------------------------------------------------------------
__global__ void build_mats(const float* __restrict__ params, _Float16* __restrict__ ws) {
  __shared__ double tg[4][6];  // per gate j: c, sn, ca, sa, cb, sb
  int s = blockIdx.x, layer = s / 3, axis = s % 3;
  int t = threadIdx.x, n = t >> 4, col = t & 15;

  if (t < 12) {
    int j = t / 3, which = t % 3;
    int q = (axis == 0) ? (11 - j) : (axis == 1) ? (7 - j) : (3 - j);
    const float* pp = params + (layer * 12 + q) * 3;
    double phi = pp[0], th = pp[1], om = pp[2];
    if (which == 0) { tg[j][0] = cos(0.5 * th);         tg[j][1] = sin(0.5 * th); }
    if (which == 1) { tg[j][2] = cos(0.5 * (phi + om)); tg[j][3] = sin(0.5 * (phi + om)); }
    if (which == 2) { tg[j][4] = cos(0.5 * (phi - om)); tg[j][5] = sin(0.5 * (phi - om)); }
  }
  __syncthreads();

  double Er = 1.0, Ei = 0.0;
  #pragma unroll
  for (int j = 0; j < 4; ++j) {
    double c = tg[j][0], sn = tg[j][1];
    double ca = tg[j][2], sa = tg[j][3], cb = tg[j][4], sb = tg[j][5];
    int nb = (n >> j) & 1, cbit = (col >> j) & 1;
    double mr, mi;
    if (!nb) {
      if (!cbit) { mr =  ca * c;  mi = -sa * c; }
      else       { mr = -cb * sn; mi = -sb * sn; }
    } else {
      if (!cbit) { mr =  cb * sn; mi = -sb * sn; }
      else       { mr =  ca * c;  mi =  sa * c; }
    }
    double nr = Er * mr - Ei * mi, ni = Er * mi + Ei * mr;
    Er = nr; Ei = ni;
  }
  int a_;
  if (axis == 0 && layer > 0) {           // CNOT fold: Gray slot order
    int kb = col >> 2, ll = col & 3;
    a_ = kb * 4 + ((ll ^ (ll >> 1)) ^ ((kb & 1) << 1));
  } else a_ = col;
  _Float16* reh = ws + s * 2048;
  _Float16* rel = reh + 512;
  _Float16* imh = reh + 1024;
  _Float16* iml = reh + 1536;
  int o0 = n * 32 + 2 * a_, o1 = o0 + 1;
  float v; _Float16 h;
  v = (float)Er;  h = (_Float16)v; reh[o0] = h; rel[o0] = (_Float16)((v - (float)h) * 2048.f);
  v = (float)-Ei; h = (_Float16)v; reh[o1] = h; rel[o1] = (_Float16)((v - (float)h) * 2048.f);
  v = (float)Ei;  h = (_Float16)v; imh[o0] = h; iml[o0] = (_Float16)((v - (float)h) * 2048.f);
  v = (float)Er;  h = (_Float16)v; imh[o1] = h; iml[o1] = (_Float16)((v - (float)h) * 2048.f);
}

// ---- paired RTZ 3-way split via v_cvt_pkrtz (r14 verbatim) ----
__device__ __forceinline__ void split3pk(float v0, float v1, u32& w0, u32& w1, u32& w2) {
  h2v p0 = __builtin_bit_cast(h2v, __builtin_amdgcn_cvt_pkrtz(v0, v1));
  float r0a = v0 - (float)p0[0];
  float r0b = v1 - (float)p0[1];
  h2v p1 = __builtin_bit_cast(h2v, __builtin_amdgcn_cvt_pkrtz(r0a * 2048.f, r0b * 2048.f));
  float r1a = r0a - (float)p1[0] * (1.f / 2048.f);
  float r1b = r0b - (float)p1[1] * (1.f / 2048.f);
  h2v p2 = __builtin_bit_cast(h2v, __builtin_amdgcn_cvt_pkrtz(r1a * 4194304.f, r1b * 4194304.f));
  w0 = __builtin_bit_cast(u32, p0);
  w1 = __builtin_bit_cast(u32, p1);
  w2 = __builtin_bit_cast(u32, p2);
}

__device__ __forceinline__ void split3x8pk(const float4& ra, const float4& rb,
                                           h8& a0, h8& a1, h8& a2) {
  uint4 w0, w1, w2;
  split3pk(ra.x, ra.y, w0.x, w1.x, w2.x);
  split3pk(ra.z, ra.w, w0.y, w1.y, w2.y);
  split3pk(rb.x, rb.y, w0.z, w1.z, w2.z);
  split3pk(rb.z, rb.w, w0.w, w1.w, w2.w);
  a0 = __builtin_bit_cast(h8, w0);
  a1 = __builtin_bit_cast(h8, w1);
  a2 = __builtin_bit_cast(h8, w2);
}

// One output part (r8/r10/r12/r14 verbatim MFMA ops, order, combine).
__device__ __forceinline__ f4 cpart(const h8& a0, const h8& a1, const h8& a2,
                                    const h8& B0, const h8& B1) {
  f4 z = {0.f, 0.f, 0.f, 0.f};
  f4 m  = __builtin_amdgcn_mfma_f32_16x16x32_f16(a0, B0, z, 0, 0, 0);
  f4 c  = __builtin_amdgcn_mfma_f32_16x16x32_f16(a1, B0, z, 0, 0, 0);
  c     = __builtin_amdgcn_mfma_f32_16x16x32_f16(a0, B1, c, 0, 0, 0);
  f4 c2 = __builtin_amdgcn_mfma_f32_16x16x32_f16(a2, B0, z, 0, 0, 0);
  c2    = __builtin_amdgcn_mfma_f32_16x16x32_f16(a1, B1, c2, 0, 0, 0);
  const float sc = 1.f / 2048.f, sc2 = 1.f / 4194304.f;
  f4 outv;
  #pragma unroll
  for (int j = 0; j < 4; ++j)
    outv[j] = fmaf(c2[j], sc2, fmaf(c[j], sc, m[j]));
  return outv;
}

// ---------------------------------------------------------------------------
// r14 VERBATIM except: red[] overlaid onto st after all state reads complete
// -> LDS exactly 32768 B -> 5 blocks/CU (was 4).
// ---------------------------------------------------------------------------
__global__ __launch_bounds__(256, 3) void circuit_kernel(
    const float* __restrict__ x, const _Float16* __restrict__ mats,
    const float* __restrict__ W, const float* __restrict__ bias,
    float* __restrict__ out) {
  __shared__ __align__(16) float2 st[4096];   // 32768 B exactly

  const int b = blockIdx.x;
  const int tid = threadIdx.x;
  const int lane = tid & 63, w = tid >> 6;
  const int r = lane & 15, kb = lane >> 4;

  // ---- init: product state of the data-encoding RY layer ----
  float cs[12], sn_[12];
  #pragma unroll
  for (int q = 0; q < 12; ++q) {
    float sv, cv;
    sincosf(0.5f * x[b * 12 + q], &sv, &cv);
    cs[11 - q] = cv; sn_[11 - q] = sv;
  }
  {
    int hb = (w << 6) | lane;
    float basep = 1.f;
    #pragma unroll
    for (int i = 0; i < 8; ++i) basep *= ((hb >> i) & 1) ? sn_[4 + i] : cs[4 + i];
    float p2[4], q2[4];
    #pragma unroll
    for (int v = 0; v < 4; ++v) {
      p2[v] = ((v & 1) ? sn_[0] : cs[0]) * ((v & 2) ? sn_[1] : cs[1]);
      q2[v] = ((v & 1) ? sn_[2] : cs[2]) * ((v & 2) ? sn_[3] : cs[3]) * basep;
    }
    #pragma unroll
    for (int g = 0; g < 4; ++g) {
      int idx = w * 1024 + lane * 16 + g * 4;
      float a0 = q2[g] * p2[0], a1 = q2[g] * p2[1];
      float a2 = q2[g] * p2[2], a3 = q2[g] * p2[3];
      *(float4*)&st[SWZA(idx)]     = make_float4(a0, 0.f, a1, 0.f);
      *(float4*)&st[SWZA(idx + 2)] = make_float4(a2, 0.f, a3, 0.f);
    }
  }
  __syncthreads();

  // fold-read constants (r4/r6/r8/r10/r12/r14 verbatim)
  const int g4r = r ^ (r >> 1);
  const int kb0 = kb & 1, kb1 = kb >> 1, m0 = r & 1;
  const int ob = ((kb1 ^ m0) << 1) | (kb0 ^ kb1);
  const int bo = r * 32 + kb * 8;

  for (int layer = 0; layer < 6; ++layer) {
    f4 TR[4], TI[4];
    const bool fold = (layer > 0);
    // ---- phase 1a: L stage (fold read), only L's B-mats hot ----
    {
      const _Float16* mbL = mats + (layer * 3 + 0) * 2048;
      h8 LbRh = *(const h8*)(mbL + bo),        LbRl = *(const h8*)(mbL + 512 + bo);
      h8 LbIh = *(const h8*)(mbL + 1024 + bo), LbIl = *(const h8*)(mbL + 1536 + bo);
      #pragma unroll
      for (int i = 0; i < 4; ++i) {
        int tile = w * 4 + i;
        int ridx;
        if (fold) {
          int oh = tile ^ (tile >> 1);
          int om = g4r ^ ((tile & 1) << 3);
          ridx = (oh << 8) | (om << 4) | (ob << 2);
        } else {
          ridx = (tile << 8) | (r << 4) | (kb << 2);
        }
        float4 ra = *(const float4*)&st[SWZA(ridx)];
        float4 rb = *(const float4*)&st[SWZA(ridx + 2)];
        h8 a0, a1, a2;
        split3x8pk(ra, rb, a0, a1, a2);
        TR[i] = cpart(a0, a1, a2, LbRh, LbRl);
        TI[i] = cpart(a0, a1, a2, LbIh, LbIl);
      }
    }
    // ---- phase 1b: M stage from registers (D_L frag IS M's A-frag) ----
    {
      const _Float16* mbM = mats + (layer * 3 + 1) * 2048;
      h8 MbRh = *(const h8*)(mbM + bo),        MbRl = *(const h8*)(mbM + 512 + bo);
      h8 MbIh = *(const h8*)(mbM + 1024 + bo), MbIl = *(const h8*)(mbM + 1536 + bo);
      #pragma unroll
      for (int i = 0; i < 4; ++i) {
        uint4 w0, w1, w2;
        split3pk(TR[i][0], TI[i][0], w0.x, w1.x, w2.x);
        split3pk(TR[i][1], TI[i][1], w0.y, w1.y, w2.y);
        split3pk(TR[i][2], TI[i][2], w0.z, w1.z, w2.z);
        split3pk(TR[i][3], TI[i][3], w0.w, w1.w, w2.w);
        h8 b0 = __builtin_bit_cast(h8, w0);
        h8 b1 = __builtin_bit_cast(h8, w1);
        h8 b2 = __builtin_bit_cast(h8, w2);
        f4 MR = cpart(b0, b1, b2, MbRh, MbRl);
        f4 MI = cpart(b0, b1, b2, MbIh, MbIl);
        TR[i] = MR; TI[i] = MI;
      }
    }
    __syncthreads();  // all S_in reads complete
    // scatter-write S_mid [m'][l'][h]: amp = (r<<8)|((4kb+j)<<4)|tile
    #pragma unroll
    for (int i = 0; i < 4; ++i) {
      int tile = w * 4 + i;
      #pragma unroll
      for (int j = 0; j < 4; ++j) {
        int amp = (r << 8) | ((4 * kb + j) << 4) | tile;
        st[SWZA(amp)] = make_float2(TR[i][j], TI[i][j]);
      }
    }
    __syncthreads();  // S_mid complete

    // ---- phase 2: H stage ----
    {
      const _Float16* mbH = mats + (layer * 3 + 2) * 2048;
      h8 HbRh = *(const h8*)(mbH + bo),        HbRl = *(const h8*)(mbH + 512 + bo);
      h8 HbIh = *(const h8*)(mbH + 1024 + bo), HbIl = *(const h8*)(mbH + 1536 + bo);
      float4 pA[4], pB[4];
      #pragma unroll
      for (int i = 0; i < 4; ++i) {
        int tile = w * 4 + i;
        int ridx = (tile << 8) | (r << 4) | (kb << 2);
        float4 ra = *(const float4*)&st[SWZA(ridx)];
        float4 rb = *(const float4*)&st[SWZA(ridx + 2)];
        h8 a0, a1, a2;
        split3x8pk(ra, rb, a0, a1, a2);
        f4 HR = cpart(a0, a1, a2, HbRh, HbRl);
        f4 HI = cpart(a0, a1, a2, HbIh, HbIl);
        pA[i] = make_float4(HR[0], HI[0], HR[1], HI[1]);
        pB[i] = make_float4(HR[2], HI[2], HR[3], HI[3]);
      }
      __syncthreads();  // all S_mid reads complete
      #pragma unroll
      for (int i = 0; i < 4; ++i) {
        int tile = w * 4 + i;
        int widx = (r << 8) | (tile << 4) | (kb << 2);
        *(float4*)&st[SWZA(widx)]     = pA[i];
        *(float4*)&st[SWZA(widx + 2)] = pB[i];
      }
      __syncthreads();  // S_out complete
    }
  }

  // ---- measurement: final CNOT folded via parity signs ----
  float psum = 0.f, A0 = 0.f, A1 = 0.f, A2 = 0.f, A3 = 0.f;
  #pragma unroll
  for (int g = 0; g < 4; ++g) {
    int idx = w * 1024 + lane * 16 + g * 4;
    float4 ra = *(const float4*)&st[SWZA(idx)];
    float4 rb = *(const float4*)&st[SWZA(idx + 2)];
    float re_[4] = {ra.x, ra.z, rb.x, rb.z};
    float im_[4] = {ra.y, ra.w, rb.y, rb.w};
    #pragma unroll
    for (int j = 0; j < 4; ++j) {
      int tt = g * 4 + j;
      float p = re_[j] * re_[j] + im_[j] * im_[j];
      psum += p;
      A0 += (__builtin_popcount((unsigned)tt) & 1) ? -p : p;
      A1 += (__builtin_popcount((unsigned)(tt >> 1)) & 1) ? -p : p;
      A2 += (__builtin_popcount((unsigned)(tt >> 2)) & 1) ? -p : p;
      A3 += (__builtin_popcount((unsigned)(tt >> 3)) & 1) ? -p : p;
    }
  }
  float zs[12];
  {
    int u = (w << 6) | lane;
    int pu = __builtin_popcount((unsigned)u) & 1;
    zs[11] = pu ? -A0 : A0;
    zs[10] = pu ? -A1 : A1;
    zs[9]  = pu ? -A2 : A2;
    zs[8]  = pu ? -A3 : A3;
    #pragma unroll
    for (int q = 0; q <= 7; ++q) {
      int sgn = __builtin_popcount((unsigned)(u >> (7 - q))) & 1;
      zs[q] = sgn ? -psum : psum;
    }
  }
  #pragma unroll
  for (int q = 0; q < 12; ++q) {
    float v = zs[q];
    #pragma unroll
    for (int off = 1; off < 64; off <<= 1) v += __shfl_xor(v, off, 64);
    zs[q] = v;
  }
  __syncthreads();  // all st reads complete; safe to overlay reduction scratch
  float* red = (float*)st;
  if (lane == 0) {
    #pragma unroll
    for (int q = 0; q < 12; ++q) red[w * 12 + q] = zs[q];
  }
  __syncthreads();
  if (tid < 12) red[48 + tid] = red[tid] + red[12 + tid] + red[24 + tid] + red[36 + tid];
  __syncthreads();
  if (tid < 64) {
    float acc = bias[tid];
    #pragma unroll
    for (int q = 0; q < 12; ++q) acc = fmaf(red[48 + q], W[tid * 12 + q], acc);
    out[b * 64 + tid] = acc;
  }
}

extern "C" void kernel_launch(void* const* d_in, const int* in_sizes, int n_in,
                              void* d_out, int out_size, void* d_ws, size_t ws_size,
                              hipStream_t stream) {
  const float* x      = (const float*)d_in[0];
  const float* params = (const float*)d_in[1];
  const float* W      = (const float*)d_in[2];
  const float* bias   = (const float*)d_in[3];
  float* out = (float*)d_out;
  _Float16* mats = (_Float16*)d_ws;  // 18 * 2048 f16 = 73728 bytes

  build_mats<<<18, 256, 0, stream>>>(params, mats);
  circuit_kernel<<<BATCH, 256, 0, stream>>>(x, mats, W, bias, out);
}